// Round 14
// baseline (168.855 us; speedup 1.0000x reference)
//
#include <hip/hip_runtime.h>

#define BB 16
#define HIMG 64
#define WIMG 64
#define CC 256
#define NHEAD 8
#define HD 32
#define NN 4096
#define PWD 65   // 2*DH+1
#define PADC 264 // qr_bf row stride (ushorts)
#define NCH 32   // k1 chunks per batch (128 rows each)

typedef short bf16x8 __attribute__((ext_vector_type(8)));
typedef float f32x4 __attribute__((ext_vector_type(4)));

__device__ __forceinline__ float elu1(float x) {
    return x > 0.0f ? x + 1.0f : __expf(x);
}
__device__ __forceinline__ float sigm(float x) {
    return 1.0f / (1.0f + __expf(-x));
}
__device__ __forceinline__ unsigned short f2bf(float f) {
    union { float f; unsigned int u; } v; v.f = f;
    unsigned int r = v.u + 0x7FFFu + ((v.u >> 16) & 1u);   // RNE
    return (unsigned short)(r >> 16);
}

// ---------------- Kernel 0: pw[n][c] = sigmoid(posw[i+1][j+1][c]) ---------------
__global__ __launch_bounds__(256) void k0_pw(
    const float* __restrict__ posw, float* __restrict__ pw)
{
    const int gid = blockIdx.x * 256 + threadIdx.x;  // 0 .. 262143
    const int n = gid >> 6;
    const int p = gid & 63;
    const int ii = n >> 6, jj = n & 63;
    const float4 v = *(const float4*)(posw + (size_t)((ii + 1) * PWD + (jj + 1)) * CC + p * 4);
    float4 r;
    r.x = sigm(v.x); r.y = sigm(v.y); r.z = sigm(v.z); r.w = sigm(v.w);
    *(float4*)(pw + (size_t)n * CC + p * 4) = r;
}

// ---------------- Kernel 1: partial kv (K_rope^T V) and ksum per chunk ----------
// grid = 512 (b x chunk), block = 512 (8 waves). R11's proven ping-pong, with
// 16-row steps: 8 barriers/block (half of R11), 4+4 float4 loads in flight per
// thread per step (double depth) -> compute window ~= HBM latency.
__global__ __launch_bounds__(512, 4) void k1_partial(
    const float* __restrict__ x2, const float* __restrict__ x3,
    const float* __restrict__ pw, float* __restrict__ pkv,
    float* __restrict__ pksum)
{
    const int blk   = blockIdx.x;          // b*NCH + chunk
    const int b     = blk >> 5;
    const int chunk = blk & 31;
    const int n0    = chunk * 128;
    const int t     = threadIdx.x;
    const bool isK  = t < 256;
    const int rgrp  = (t & 255) >> 6;      // 0..3 (row group)
    const int slot  = t & 63;              // float4 slot within a row

    const int h  = t >> 6;                 // compute: head 0..7 (one wave per head)
    const int l  = t & 63;
    const int dq = l >> 3;                 // d-quad
    const int eq = l & 7;                  // e-quad

    __shared__ float kr_lds[2][16][CC];    // 32 KiB
    __shared__ float v_lds[2][16][CC];     // 32 KiB
    __shared__ float ksum_lds[4][CC];      // 4 KiB

    float acc[4][4];
#pragma unroll
    for (int a = 0; a < 4; ++a)
#pragma unroll
        for (int c = 0; c < 4; ++c) acc[a][c] = 0.0f;
    float ks0 = 0.f, ks1 = 0.f, ks2 = 0.f, ks3 = 0.f;

    const float* x2b = x2 + (size_t)b * NN * CC;
    const float* x3b = x3 + (size_t)b * NN * CC;

    float4 kx[4], pv[4], vx[4];

#define K1_LOAD(sS)                                                           \
    do {                                                                      \
        const int r0_ = n0 + (sS) * 16;                                       \
        if (isK) {                                                            \
            _Pragma("unroll")                                                 \
            for (int i_ = 0; i_ < 4; ++i_) {                                  \
                const int n_ = r0_ + rgrp + 4 * i_;                           \
                kx[i_] = *(const float4*)(x2b + (size_t)n_ * CC + slot * 4);  \
            }                                                                 \
            _Pragma("unroll")                                                 \
            for (int i_ = 0; i_ < 4; ++i_) {                                  \
                const int n_ = r0_ + rgrp + 4 * i_;                           \
                pv[i_] = *(const float4*)(pw + (size_t)n_ * CC + slot * 4);   \
            }                                                                 \
        } else {                                                              \
            _Pragma("unroll")                                                 \
            for (int i_ = 0; i_ < 4; ++i_) {                                  \
                const int n_ = r0_ + rgrp + 4 * i_;                           \
                vx[i_] = *(const float4*)(x3b + (size_t)n_ * CC + slot * 4);  \
            }                                                                 \
        }                                                                     \
    } while (0)

    K1_LOAD(0);
    int buf = 0;
    for (int s = 0; s < 8; ++s) {
        // ---- write current regs to LDS[buf] ----
        if (isK) {
#pragma unroll
            for (int i = 0; i < 4; ++i) {
                const int row = rgrp + 4 * i;
                float k0 = elu1(kx[i].x), k1 = elu1(kx[i].y);
                float k2 = elu1(kx[i].z), k3 = elu1(kx[i].w);
                ks0 += k0; ks1 += k1; ks2 += k2; ks3 += k3;
                float4 kr;
                kr.x = k0 * pv[i].x; kr.y = k1 * pv[i].y;
                kr.z = k2 * pv[i].z; kr.w = k3 * pv[i].w;
                *(float4*)(&kr_lds[buf][row][slot * 4]) = kr;
            }
        } else {
#pragma unroll
            for (int i = 0; i < 4; ++i)
                *(float4*)(&v_lds[buf][rgrp + 4 * i][slot * 4]) = vx[i];
        }
        __syncthreads();
        // ---- issue loads for step s+1 (in flight during compute) ----
        if (s + 1 < 8) K1_LOAD(s + 1);
        // ---- compute from LDS[buf]: wave h, lane (dq,eq): 4x4 tile ----
#pragma unroll
        for (int r = 0; r < 16; ++r) {
            const float4 k4 = *(const float4*)(&kr_lds[buf][r][h * HD + dq * 4]);
            const float4 v4 = *(const float4*)(&v_lds[buf][r][h * HD + eq * 4]);
            const float kd[4] = {k4.x, k4.y, k4.z, k4.w};
            const float ve[4] = {v4.x, v4.y, v4.z, v4.w};
#pragma unroll
            for (int a = 0; a < 4; ++a)
#pragma unroll
                for (int c = 0; c < 4; ++c)
                    acc[a][c] = fmaf(kd[a], ve[c], acc[a][c]);
        }
        buf ^= 1;
    }
#undef K1_LOAD

    if (isK) {
        ksum_lds[rgrp][slot * 4 + 0] = ks0;
        ksum_lds[rgrp][slot * 4 + 1] = ks1;
        ksum_lds[rgrp][slot * 4 + 2] = ks2;
        ksum_lds[rgrp][slot * 4 + 3] = ks3;
    }
    __syncthreads();
    if (t < CC) {
        pksum[(size_t)blk * CC + t] = ksum_lds[0][t] + ksum_lds[1][t] +
                                      ksum_lds[2][t] + ksum_lds[3][t];
    }

    // pkv layout per blk: [8 heads][32 d][32 e]
    float* dst = pkv + (size_t)blk * (NHEAD * HD * HD) + h * (HD * HD);
#pragma unroll
    for (int a = 0; a < 4; ++a) {
        float4 w4 = {acc[a][0], acc[a][1], acc[a][2], acc[a][3]};
        *(float4*)(dst + (dq * 4 + a) * HD + eq * 4) = w4;
    }
}

// ---------------- Kernel 2: reduce partials; emit kvbT (bf16, [b][h][e][d]) -----
// grid = 512, block = 256. pkv o-layout: h*1024 + d*32 + e.
__global__ __launch_bounds__(256) void k2_reduce(
    const float* __restrict__ pkv, const float* __restrict__ pksum,
    unsigned short* __restrict__ kvbT, float* __restrict__ kmean)
{
    const int gid = blockIdx.x * 256 + threadIdx.x;   // over B*8192
    const int b = gid >> 13;
    const int o = gid & 8191;
    float s = 0.f;
#pragma unroll 4
    for (int c = 0; c < NCH; ++c)
        s += pkv[(size_t)(b * NCH + c) * (NHEAD * HD * HD) + o];
    const int hh = o >> 10, d = (o >> 5) & 31, e = o & 31;
    kvbT[(((size_t)b * NHEAD + hh) * HD + e) * HD + d] = f2bf(s * (1.0f / NN));
    if (o < CC) {
        float ss = 0.f;
#pragma unroll 4
        for (int c = 0; c < NCH; ++c)
            ss += pksum[(size_t)(b * NCH + c) * CC + o];
        kmean[b * CC + o] = ss * (1.0f / NN);
    }
}

// ---------------- Kernel 3: out = MFMA((qr*z) @ kv) + LePE ----------------------
// grid = B*256 (quarter image row each), block = 256 (4 waves)
__global__ __launch_bounds__(256, 2) void k3_out(
    const float* __restrict__ x1, const float* __restrict__ x3,
    const float* __restrict__ pw, const unsigned short* __restrict__ kvbT,
    const float* __restrict__ kmean, const float* __restrict__ lw,
    const float* __restrict__ lb, float* __restrict__ out)
{
    const int blk  = blockIdx.x;      // b*256 + irow*4 + jq
    const int b    = blk >> 8;
    const int irow = (blk >> 2) & 63;
    const int jq   = blk & 3;
    const int j0   = jq << 4;         // 0, 16, 32, 48
    const int t    = threadIdx.x;

    __shared__ unsigned short qr_bf[16 * PADC];   // (qr * z) in bf16, 8.4 KiB
    __shared__ float attn_lds[16][CC];            // 16 KiB

    float wreg[9];
#pragma unroll
    for (int q = 0; q < 9; ++q) wreg[q] = lw[t * 9 + q];
    const float bias = lb[t];

    // ---- stage: q_rope * z  -> bf16 LDS (z folded in; known after shfl reduce) ----
    {
        const int p    = t & 63;       // float4 slot within a pixel's 256 channels
        const int pixo = t >> 6;       // 0..3
        const float4 km4 = *(const float4*)(kmean + b * CC + p * 4);
        const float* x1b = x1 + ((size_t)b * NN + (size_t)irow * 64 + j0) * CC;
        const float* pwb = pw + ((size_t)irow * 64 + j0) * CC;
        float4 xv[4], pvv[4];
#pragma unroll
        for (int s = 0; s < 4; ++s)
            xv[s] = *(const float4*)(x1b + (size_t)(s * 4 + pixo) * CC + p * 4);
#pragma unroll
        for (int s = 0; s < 4; ++s)
            pvv[s] = *(const float4*)(pwb + (size_t)(s * 4 + pixo) * CC + p * 4);
#pragma unroll
        for (int s = 0; s < 4; ++s) {
            const int pix = s * 4 + pixo;   // 0..15 (local)
            float4 q4;
            q4.x = elu1(xv[s].x); q4.y = elu1(xv[s].y);
            q4.z = elu1(xv[s].z); q4.w = elu1(xv[s].w);
            float zp = q4.x * km4.x + q4.y * km4.y + q4.z * km4.z + q4.w * km4.w;
            zp += __shfl_xor(zp, 1);
            zp += __shfl_xor(zp, 2);
            zp += __shfl_xor(zp, 4);        // all 8 lanes of this head have the sum
            const float zin = 1.0f / (zp + 1e-6f);
            ushort4 u;
            u.x = f2bf(q4.x * pvv[s].x * zin);
            u.y = f2bf(q4.y * pvv[s].y * zin);
            u.z = f2bf(q4.z * pvv[s].z * zin);
            u.w = f2bf(q4.w * pvv[s].w * zin);
            *(ushort4*)(&qr_bf[pix * PADC + p * 4]) = u;
        }
    }

    // ---- halo loads issued BEFORE the barrier: cannot be sunk past it ----
    const bool hasU = irow > 0, hasD = irow < 63;
    const float* rU = x3 + ((size_t)b * NN + (size_t)(irow - 1) * 64 + j0) * CC + t;
    const float* rM = x3 + ((size_t)b * NN + (size_t)irow * 64 + j0) * CC + t;
    const float* rD = x3 + ((size_t)b * NN + (size_t)(irow + 1) * 64 + j0) * CC + t;

    float cu[2][10], cm[2][10], cd[2][10];
#pragma unroll
    for (int tt = 0; tt < 2; ++tt)
#pragma unroll
        for (int q = 0; q < 10; ++q) {
            const int col = tt * 8 + q - 1;     // local col in [-1, 16]
            const int g   = j0 + col;           // global col in [-1, 64]
            const bool ok = (g >= 0) && (g < 64);
            const long off = (long)col * CC;
            cm[tt][q] = ok ? rM[off] : 0.f;
            cu[tt][q] = (ok && hasU) ? rU[off] : 0.f;
            cd[tt][q] = (ok && hasD) ? rD[off] : 0.f;
        }

    __syncthreads();

    // ---- MFMA phase: wave w covers heads 2w,2w+1 over all 16 pixels ----
    {
        const int w  = t >> 6;
        const int l  = t & 63;
        const int lr = l & 15;     // A row (pixel) / B col / D col
        const int lg = l >> 4;     // k-group

        bf16x8 af0 = *(const bf16x8*)(&qr_bf[lr * PADC + (w * 2 + 0) * HD + lg * 8]);
        bf16x8 af1 = *(const bf16x8*)(&qr_bf[lr * PADC + (w * 2 + 1) * HD + lg * 8]);

        f32x4 acc[4];
#pragma unroll
        for (int ct = 0; ct < 4; ++ct) {
            const int head = w * 2 + (ct >> 1);
            const int cl   = (ct & 1) * 16 + lr;
            const bf16x8 bf = *(const bf16x8*)(kvbT +
                (((size_t)b * NHEAD + head) * HD + cl) * HD + lg * 8);
            f32x4 z4 = {0.f, 0.f, 0.f, 0.f};
            acc[ct] = __builtin_amdgcn_mfma_f32_16x16x32_bf16(
                (ct < 2) ? af0 : af1, bf, z4, 0, 0, 0);
        }
#pragma unroll
        for (int ct = 0; ct < 4; ++ct) {
            const int c = (w * 2 + (ct >> 1)) * HD + (ct & 1) * 16 + lr;
#pragma unroll
            for (int r = 0; r < 4; ++r)
                attn_lds[lg * 4 + r][c] = acc[ct][r];
        }
    }

    __syncthreads();

    // ---- epilogue: lepe (registers already loaded) + attn + store ----
    float* ob = out + ((size_t)b * NN + (size_t)irow * 64 + j0) * CC + t;
#pragma unroll
    for (int tt = 0; tt < 2; ++tt) {
#pragma unroll
        for (int q = 0; q < 8; ++q) {
            const int jl = tt * 8 + q;          // local pixel 0..15
            float lepe = bias
                + wreg[0] * cu[tt][q] + wreg[1] * cu[tt][q + 1] + wreg[2] * cu[tt][q + 2]
                + wreg[3] * cm[tt][q] + wreg[4] * cm[tt][q + 1] + wreg[5] * cm[tt][q + 2]
                + wreg[6] * cd[tt][q] + wreg[7] * cd[tt][q + 1] + wreg[8] * cd[tt][q + 2];
            __builtin_nontemporal_store(attn_lds[jl][t] + lepe, ob + (long)jl * CC);
        }
    }
}

extern "C" void kernel_launch(void* const* d_in, const int* in_sizes, int n_in,
                              void* d_out, int out_size, void* d_ws, size_t ws_size,
                              hipStream_t stream) {
    const float* x1   = (const float*)d_in[0];
    const float* x2   = (const float*)d_in[1];
    const float* x3   = (const float*)d_in[2];
    const float* posw = (const float*)d_in[3];
    const float* lw   = (const float*)d_in[4];
    const float* lb   = (const float*)d_in[5];
    float* out = (float*)d_out;

    // ws layout: pw | pkv | pksum | kmean | kvbT(ushort)  (~21.6 MB)
    const size_t pw_sz = (size_t)NN * CC;                   // 1M floats
    float* pwb   = (float*)d_ws;
    float* pkv   = pwb + pw_sz;                             // 16*NCH * 8192
    float* pksum = pkv + (size_t)16 * NCH * 8192;           // 16*NCH * 256
    float* kmean = pksum + (size_t)16 * NCH * 256;          // 16 * 256
    unsigned short* kvbT = (unsigned short*)(kmean + (size_t)16 * 256);  // 16*8192

    k0_pw<<<1024, 256, 0, stream>>>(posw, pwb);
    k1_partial<<<BB * NCH, 512, 0, stream>>>(x2, x3, pwb, pkv, pksum);
    k2_reduce<<<512, 256, 0, stream>>>(pkv, pksum, kvbT, kmean);
    k3_out<<<BB * 256, 256, 0, stream>>>(x1, x3, pwb, kvbT, kmean, lw, lb, out);
}

// Round 15
// 95.617 us; speedup vs baseline: 1.7660x; 1.7660x over previous
//
#include <hip/hip_runtime.h>

#define BB 16
#define HIMG 64
#define WIMG 64
#define CC 256
#define NHEAD 8
#define HD 32
#define NN 4096
#define PWD 65   // 2*DH+1
#define PADC 264 // qr_bf row stride (ushorts)
#define NCH 32   // k1 chunks per batch (128 rows each)

typedef short bf16x8 __attribute__((ext_vector_type(8)));
typedef float f32x4 __attribute__((ext_vector_type(4)));

__device__ __forceinline__ float elu1(float x) {
    return x > 0.0f ? x + 1.0f : __expf(x);
}
__device__ __forceinline__ float sigm(float x) {
    return 1.0f / (1.0f + __expf(-x));
}
__device__ __forceinline__ unsigned short f2bf(float f) {
    union { float f; unsigned int u; } v; v.f = f;
    unsigned int r = v.u + 0x7FFFu + ((v.u >> 16) & 1u);   // RNE
    return (unsigned short)(r >> 16);
}

// ---------------- Kernel 0: pw[n][c] = sigmoid(posw[i+1][j+1][c]) ---------------
__global__ __launch_bounds__(256) void k0_pw(
    const float* __restrict__ posw, float* __restrict__ pw)
{
    const int gid = blockIdx.x * 256 + threadIdx.x;  // 0 .. 262143
    const int n = gid >> 6;
    const int p = gid & 63;
    const int ii = n >> 6, jj = n & 63;
    const float4 v = *(const float4*)(posw + (size_t)((ii + 1) * PWD + (jj + 1)) * CC + p * 4);
    float4 r;
    r.x = sigm(v.x); r.y = sigm(v.y); r.z = sigm(v.z); r.w = sigm(v.w);
    *(float4*)(pw + (size_t)n * CC + p * 4) = r;
}

// ---------------- Kernel 1: partial kv (K_rope^T V) and ksum per chunk ----------
// grid = 512 (b x chunk), block = 512 (8 waves). Ping-pong, 16-row steps
// (8 barriers/block), 4+4 float4 loads in flight per thread per step.
// PLAIN launch bounds: __launch_bounds__(512,4) capped VGPR at 64 -> R14 spill.
// LDS (68 KiB) caps occupancy at 2 blocks/CU = 16 waves regardless.
__global__ __launch_bounds__(512) void k1_partial(
    const float* __restrict__ x2, const float* __restrict__ x3,
    const float* __restrict__ pw, float* __restrict__ pkv,
    float* __restrict__ pksum)
{
    const int blk   = blockIdx.x;          // b*NCH + chunk
    const int b     = blk >> 5;
    const int chunk = blk & 31;
    const int n0    = chunk * 128;
    const int t     = threadIdx.x;
    const bool isK  = t < 256;
    const int rgrp  = (t & 255) >> 6;      // 0..3 (row group)
    const int slot  = t & 63;              // float4 slot within a row

    const int h  = t >> 6;                 // compute: head 0..7 (one wave per head)
    const int l  = t & 63;
    const int dq = l >> 3;                 // d-quad
    const int eq = l & 7;                  // e-quad

    __shared__ float kr_lds[2][16][CC];    // 32 KiB
    __shared__ float v_lds[2][16][CC];     // 32 KiB
    __shared__ float ksum_lds[4][CC];      // 4 KiB

    float acc[4][4];
#pragma unroll
    for (int a = 0; a < 4; ++a)
#pragma unroll
        for (int c = 0; c < 4; ++c) acc[a][c] = 0.0f;
    float ks0 = 0.f, ks1 = 0.f, ks2 = 0.f, ks3 = 0.f;

    const float* x2b = x2 + (size_t)b * NN * CC;
    const float* x3b = x3 + (size_t)b * NN * CC;

    float4 kx[4], pv[4], vx[4];

#define K1_LOAD(sS)                                                           \
    do {                                                                      \
        const int r0_ = n0 + (sS) * 16;                                       \
        if (isK) {                                                            \
            _Pragma("unroll")                                                 \
            for (int i_ = 0; i_ < 4; ++i_) {                                  \
                const int n_ = r0_ + rgrp + 4 * i_;                           \
                kx[i_] = *(const float4*)(x2b + (size_t)n_ * CC + slot * 4);  \
            }                                                                 \
            _Pragma("unroll")                                                 \
            for (int i_ = 0; i_ < 4; ++i_) {                                  \
                const int n_ = r0_ + rgrp + 4 * i_;                           \
                pv[i_] = *(const float4*)(pw + (size_t)n_ * CC + slot * 4);   \
            }                                                                 \
        } else {                                                              \
            _Pragma("unroll")                                                 \
            for (int i_ = 0; i_ < 4; ++i_) {                                  \
                const int n_ = r0_ + rgrp + 4 * i_;                           \
                vx[i_] = *(const float4*)(x3b + (size_t)n_ * CC + slot * 4);  \
            }                                                                 \
        }                                                                     \
    } while (0)

    K1_LOAD(0);
    int buf = 0;
    for (int s = 0; s < 8; ++s) {
        // ---- write current regs to LDS[buf] ----
        if (isK) {
#pragma unroll
            for (int i = 0; i < 4; ++i) {
                const int row = rgrp + 4 * i;
                float k0 = elu1(kx[i].x), k1 = elu1(kx[i].y);
                float k2 = elu1(kx[i].z), k3 = elu1(kx[i].w);
                ks0 += k0; ks1 += k1; ks2 += k2; ks3 += k3;
                float4 kr;
                kr.x = k0 * pv[i].x; kr.y = k1 * pv[i].y;
                kr.z = k2 * pv[i].z; kr.w = k3 * pv[i].w;
                *(float4*)(&kr_lds[buf][row][slot * 4]) = kr;
            }
        } else {
#pragma unroll
            for (int i = 0; i < 4; ++i)
                *(float4*)(&v_lds[buf][rgrp + 4 * i][slot * 4]) = vx[i];
        }
        __syncthreads();
        // ---- issue loads for step s+1 (in flight during compute) ----
        if (s + 1 < 8) K1_LOAD(s + 1);
        // ---- compute from LDS[buf]: wave h, lane (dq,eq): 4x4 tile ----
#pragma unroll
        for (int r = 0; r < 16; ++r) {
            const float4 k4 = *(const float4*)(&kr_lds[buf][r][h * HD + dq * 4]);
            const float4 v4 = *(const float4*)(&v_lds[buf][r][h * HD + eq * 4]);
            const float kd[4] = {k4.x, k4.y, k4.z, k4.w};
            const float ve[4] = {v4.x, v4.y, v4.z, v4.w};
#pragma unroll
            for (int a = 0; a < 4; ++a)
#pragma unroll
                for (int c = 0; c < 4; ++c)
                    acc[a][c] = fmaf(kd[a], ve[c], acc[a][c]);
        }
        buf ^= 1;
    }
#undef K1_LOAD

    if (isK) {
        ksum_lds[rgrp][slot * 4 + 0] = ks0;
        ksum_lds[rgrp][slot * 4 + 1] = ks1;
        ksum_lds[rgrp][slot * 4 + 2] = ks2;
        ksum_lds[rgrp][slot * 4 + 3] = ks3;
    }
    __syncthreads();
    if (t < CC) {
        pksum[(size_t)blk * CC + t] = ksum_lds[0][t] + ksum_lds[1][t] +
                                      ksum_lds[2][t] + ksum_lds[3][t];
    }

    // pkv layout per blk: [8 heads][32 d][32 e]
    float* dst = pkv + (size_t)blk * (NHEAD * HD * HD) + h * (HD * HD);
#pragma unroll
    for (int a = 0; a < 4; ++a) {
        float4 w4 = {acc[a][0], acc[a][1], acc[a][2], acc[a][3]};
        *(float4*)(dst + (dq * 4 + a) * HD + eq * 4) = w4;
    }
}

// ---------------- Kernel 2: reduce partials; emit kvbT (bf16, [b][h][e][d]) -----
// grid = 512, block = 256. pkv o-layout: h*1024 + d*32 + e.
__global__ __launch_bounds__(256) void k2_reduce(
    const float* __restrict__ pkv, const float* __restrict__ pksum,
    unsigned short* __restrict__ kvbT, float* __restrict__ kmean)
{
    const int gid = blockIdx.x * 256 + threadIdx.x;   // over B*8192
    const int b = gid >> 13;
    const int o = gid & 8191;
    float s = 0.f;
#pragma unroll 4
    for (int c = 0; c < NCH; ++c)
        s += pkv[(size_t)(b * NCH + c) * (NHEAD * HD * HD) + o];
    const int hh = o >> 10, d = (o >> 5) & 31, e = o & 31;
    kvbT[(((size_t)b * NHEAD + hh) * HD + e) * HD + d] = f2bf(s * (1.0f / NN));
    if (o < CC) {
        float ss = 0.f;
#pragma unroll 4
        for (int c = 0; c < NCH; ++c)
            ss += pksum[(size_t)(b * NCH + c) * CC + o];
        kmean[b * CC + o] = ss * (1.0f / NN);
    }
}

// ---------------- Kernel 3: out = MFMA((qr*z) @ kv) + LePE ----------------------
// grid = B*256 (quarter image row each), block = 256 (4 waves)
__global__ __launch_bounds__(256, 2) void k3_out(
    const float* __restrict__ x1, const float* __restrict__ x3,
    const float* __restrict__ pw, const unsigned short* __restrict__ kvbT,
    const float* __restrict__ kmean, const float* __restrict__ lw,
    const float* __restrict__ lb, float* __restrict__ out)
{
    const int blk  = blockIdx.x;      // b*256 + irow*4 + jq
    const int b    = blk >> 8;
    const int irow = (blk >> 2) & 63;
    const int jq   = blk & 3;
    const int j0   = jq << 4;         // 0, 16, 32, 48
    const int t    = threadIdx.x;

    __shared__ unsigned short qr_bf[16 * PADC];   // (qr * z) in bf16, 8.4 KiB
    __shared__ float attn_lds[16][CC];            // 16 KiB

    float wreg[9];
#pragma unroll
    for (int q = 0; q < 9; ++q) wreg[q] = lw[t * 9 + q];
    const float bias = lb[t];

    // ---- stage: q_rope * z  -> bf16 LDS (z folded in; known after shfl reduce) ----
    {
        const int p    = t & 63;       // float4 slot within a pixel's 256 channels
        const int pixo = t >> 6;       // 0..3
        const float4 km4 = *(const float4*)(kmean + b * CC + p * 4);
        const float* x1b = x1 + ((size_t)b * NN + (size_t)irow * 64 + j0) * CC;
        const float* pwb = pw + ((size_t)irow * 64 + j0) * CC;
        float4 xv[4], pvv[4];
#pragma unroll
        for (int s = 0; s < 4; ++s)
            xv[s] = *(const float4*)(x1b + (size_t)(s * 4 + pixo) * CC + p * 4);
#pragma unroll
        for (int s = 0; s < 4; ++s)
            pvv[s] = *(const float4*)(pwb + (size_t)(s * 4 + pixo) * CC + p * 4);
#pragma unroll
        for (int s = 0; s < 4; ++s) {
            const int pix = s * 4 + pixo;   // 0..15 (local)
            float4 q4;
            q4.x = elu1(xv[s].x); q4.y = elu1(xv[s].y);
            q4.z = elu1(xv[s].z); q4.w = elu1(xv[s].w);
            float zp = q4.x * km4.x + q4.y * km4.y + q4.z * km4.z + q4.w * km4.w;
            zp += __shfl_xor(zp, 1);
            zp += __shfl_xor(zp, 2);
            zp += __shfl_xor(zp, 4);        // all 8 lanes of this head have the sum
            const float zin = 1.0f / (zp + 1e-6f);
            ushort4 u;
            u.x = f2bf(q4.x * pvv[s].x * zin);
            u.y = f2bf(q4.y * pvv[s].y * zin);
            u.z = f2bf(q4.z * pvv[s].z * zin);
            u.w = f2bf(q4.w * pvv[s].w * zin);
            *(ushort4*)(&qr_bf[pix * PADC + p * 4]) = u;
        }
    }

    // ---- halo loads issued BEFORE the barrier: cannot be sunk past it ----
    const bool hasU = irow > 0, hasD = irow < 63;
    const float* rU = x3 + ((size_t)b * NN + (size_t)(irow - 1) * 64 + j0) * CC + t;
    const float* rM = x3 + ((size_t)b * NN + (size_t)irow * 64 + j0) * CC + t;
    const float* rD = x3 + ((size_t)b * NN + (size_t)(irow + 1) * 64 + j0) * CC + t;

    float cu[2][10], cm[2][10], cd[2][10];
#pragma unroll
    for (int tt = 0; tt < 2; ++tt)
#pragma unroll
        for (int q = 0; q < 10; ++q) {
            const int col = tt * 8 + q - 1;     // local col in [-1, 16]
            const int g   = j0 + col;           // global col in [-1, 64]
            const bool ok = (g >= 0) && (g < 64);
            const long off = (long)col * CC;
            cm[tt][q] = ok ? rM[off] : 0.f;
            cu[tt][q] = (ok && hasU) ? rU[off] : 0.f;
            cd[tt][q] = (ok && hasD) ? rD[off] : 0.f;
        }

    __syncthreads();

    // ---- MFMA phase: wave w covers heads 2w,2w+1 over all 16 pixels ----
    {
        const int w  = t >> 6;
        const int l  = t & 63;
        const int lr = l & 15;     // A row (pixel) / B col / D col
        const int lg = l >> 4;     // k-group

        bf16x8 af0 = *(const bf16x8*)(&qr_bf[lr * PADC + (w * 2 + 0) * HD + lg * 8]);
        bf16x8 af1 = *(const bf16x8*)(&qr_bf[lr * PADC + (w * 2 + 1) * HD + lg * 8]);

        f32x4 acc[4];
#pragma unroll
        for (int ct = 0; ct < 4; ++ct) {
            const int head = w * 2 + (ct >> 1);
            const int cl   = (ct & 1) * 16 + lr;
            const bf16x8 bf = *(const bf16x8*)(kvbT +
                (((size_t)b * NHEAD + head) * HD + cl) * HD + lg * 8);
            f32x4 z4 = {0.f, 0.f, 0.f, 0.f};
            acc[ct] = __builtin_amdgcn_mfma_f32_16x16x32_bf16(
                (ct < 2) ? af0 : af1, bf, z4, 0, 0, 0);
        }
#pragma unroll
        for (int ct = 0; ct < 4; ++ct) {
            const int c = (w * 2 + (ct >> 1)) * HD + (ct & 1) * 16 + lr;
#pragma unroll
            for (int r = 0; r < 4; ++r)
                attn_lds[lg * 4 + r][c] = acc[ct][r];
        }
    }

    __syncthreads();

    // ---- epilogue: lepe (registers already loaded) + attn + store ----
    float* ob = out + ((size_t)b * NN + (size_t)irow * 64 + j0) * CC + t;
#pragma unroll
    for (int tt = 0; tt < 2; ++tt) {
#pragma unroll
        for (int q = 0; q < 8; ++q) {
            const int jl = tt * 8 + q;          // local pixel 0..15
            float lepe = bias
                + wreg[0] * cu[tt][q] + wreg[1] * cu[tt][q + 1] + wreg[2] * cu[tt][q + 2]
                + wreg[3] * cm[tt][q] + wreg[4] * cm[tt][q + 1] + wreg[5] * cm[tt][q + 2]
                + wreg[6] * cd[tt][q] + wreg[7] * cd[tt][q + 1] + wreg[8] * cd[tt][q + 2];
            __builtin_nontemporal_store(attn_lds[jl][t] + lepe, ob + (long)jl * CC);
        }
    }
}

extern "C" void kernel_launch(void* const* d_in, const int* in_sizes, int n_in,
                              void* d_out, int out_size, void* d_ws, size_t ws_size,
                              hipStream_t stream) {
    const float* x1   = (const float*)d_in[0];
    const float* x2   = (const float*)d_in[1];
    const float* x3   = (const float*)d_in[2];
    const float* posw = (const float*)d_in[3];
    const float* lw   = (const float*)d_in[4];
    const float* lb   = (const float*)d_in[5];
    float* out = (float*)d_out;

    // ws layout: pw | pkv | pksum | kmean | kvbT(ushort)  (~21.6 MB)
    const size_t pw_sz = (size_t)NN * CC;                   // 1M floats
    float* pwb   = (float*)d_ws;
    float* pkv   = pwb + pw_sz;                             // 16*NCH * 8192
    float* pksum = pkv + (size_t)16 * NCH * 8192;           // 16*NCH * 256
    float* kmean = pksum + (size_t)16 * NCH * 256;          // 16 * 256
    unsigned short* kvbT = (unsigned short*)(kmean + (size_t)16 * 256);  // 16*8192

    k0_pw<<<1024, 256, 0, stream>>>(posw, pwb);
    k1_partial<<<BB * NCH, 512, 0, stream>>>(x2, x3, pwb, pkv, pksum);
    k2_reduce<<<512, 256, 0, stream>>>(pkv, pksum, kvbT, kmean);
    k3_out<<<BB * 256, 256, 0, stream>>>(x1, x3, pwb, kvbT, kmean, lw, lb, out);
}

// Round 16
// 81.905 us; speedup vs baseline: 2.0616x; 1.1674x over previous
//
#include <hip/hip_runtime.h>

#define BB 16
#define HIMG 64
#define WIMG 64
#define CC 256
#define NHEAD 8
#define HD 32
#define NN 4096
#define PWD 65   // 2*DH+1
#define PADC 264 // qr_bf row stride (ushorts)
#define NCH 32   // k1 chunks per batch (128 rows each)

typedef short bf16x8 __attribute__((ext_vector_type(8)));
typedef float f32x4 __attribute__((ext_vector_type(4)));

__device__ __forceinline__ float elu1(float x) {
    return x > 0.0f ? x + 1.0f : __expf(x);
}
__device__ __forceinline__ float sigm(float x) {
    return 1.0f / (1.0f + __expf(-x));
}
__device__ __forceinline__ unsigned short f2bf(float f) {
    union { float f; unsigned int u; } v; v.f = f;
    unsigned int r = v.u + 0x7FFFu + ((v.u >> 16) & 1u);   // RNE
    return (unsigned short)(r >> 16);
}

// ---------------- Kernel 0: pw[n][c] = sigmoid(posw[i+1][j+1][c]) ---------------
__global__ __launch_bounds__(256) void k0_pw(
    const float* __restrict__ posw, float* __restrict__ pw)
{
    const int gid = blockIdx.x * 256 + threadIdx.x;  // 0 .. 262143
    const int n = gid >> 6;
    const int p = gid & 63;
    const int ii = n >> 6, jj = n & 63;
    const float4 v = *(const float4*)(posw + (size_t)((ii + 1) * PWD + (jj + 1)) * CC + p * 4);
    float4 r;
    r.x = sigm(v.x); r.y = sigm(v.y); r.z = sigm(v.z); r.w = sigm(v.w);
    *(float4*)(pw + (size_t)n * CC + p * 4) = r;
}

// ---------------- Kernel 1: partial kv — no LDS, no barriers, fragment loads ----
// grid = 512 (b x chunk128), block = 256 (4 waves). Wave wv -> heads {2wv,2wv+1}.
// Lane l loads A/B fragments DIRECTLY from global in MFMA lane order:
//   frag element j = x[n0 + (l>>4)*8 + j][chhalf*16 + (l&15)]   (scalar loads,
//   each instr = 4 rows x 64B contiguous; block consumes every line exactly once).
// Per 32-row subtile per wave: 96 independent loads, elu*pw -> bf16 pack,
// 8x mfma_16x16x32_bf16. ksum per-lane + shfl_xor. Zero LDS. Zero barriers.
__global__ __launch_bounds__(256) void k1_partial(
    const float* __restrict__ x2, const float* __restrict__ x3,
    const float* __restrict__ pw, float* __restrict__ pkv,
    float* __restrict__ pksum)
{
    const int t     = threadIdx.x;
    const int wv    = t >> 6;              // 0..3 -> heads 2wv, 2wv+1
    const int blk   = blockIdx.x;          // b*NCH + chunk
    const int b     = blk >> 5;
    const int chunk = blk & 31;
    const int l     = t & 63;
    const int lr    = l & 15;              // fragment row/col within 16
    const int lg    = l >> 4;              // k-group: rows lg*8 + j

    const size_t bb = (size_t)b * NN * CC;

    f32x4 acc[2][4];
#pragma unroll
    for (int hh = 0; hh < 2; ++hh)
#pragma unroll
        for (int tl = 0; tl < 4; ++tl)
            acc[hh][tl] = (f32x4){0.f, 0.f, 0.f, 0.f};
    float ks[2][2] = {{0.f, 0.f}, {0.f, 0.f}};

    for (int s = 0; s < 4; ++s) {
        const int n0 = chunk * 128 + s * 32 + lg * 8;   // this lane's row base

        float kf[2][2][8], pf[2][2][8], vf[2][2][8];
        // ---- all 96 loads issued up-front, fully independent ----
#pragma unroll
        for (int hh = 0; hh < 2; ++hh)
#pragma unroll
            for (int dh = 0; dh < 2; ++dh) {
                const int ch = (wv * 2 + hh) * HD + dh * 16 + lr;
                const float* pk = x2 + bb + (size_t)n0 * CC + ch;
#pragma unroll
                for (int j = 0; j < 8; ++j) kf[hh][dh][j] = pk[j * CC];
            }
#pragma unroll
        for (int hh = 0; hh < 2; ++hh)
#pragma unroll
            for (int dh = 0; dh < 2; ++dh) {
                const int ch = (wv * 2 + hh) * HD + dh * 16 + lr;
                const float* pp = pw + (size_t)n0 * CC + ch;
#pragma unroll
                for (int j = 0; j < 8; ++j) pf[hh][dh][j] = pp[j * CC];
            }
#pragma unroll
        for (int hh = 0; hh < 2; ++hh)
#pragma unroll
            for (int eh = 0; eh < 2; ++eh) {
                const int ch = (wv * 2 + hh) * HD + eh * 16 + lr;
                const float* pv = x3 + bb + (size_t)n0 * CC + ch;
#pragma unroll
                for (int j = 0; j < 8; ++j) vf[hh][eh][j] = pv[j * CC];
            }

        // ---- transform + MFMA ----
#pragma unroll
        for (int hh = 0; hh < 2; ++hh) {
            union { bf16x8 v8; unsigned short u[8]; } ka[2], vb[2];
#pragma unroll
            for (int dh = 0; dh < 2; ++dh)
#pragma unroll
                for (int j = 0; j < 8; ++j) {
                    const float e = elu1(kf[hh][dh][j]);
                    ks[hh][dh] += e;
                    ka[dh].u[j] = f2bf(e * pf[hh][dh][j]);
                }
#pragma unroll
            for (int eh = 0; eh < 2; ++eh)
#pragma unroll
                for (int j = 0; j < 8; ++j)
                    vb[eh].u[j] = f2bf(vf[hh][eh][j]);
#pragma unroll
            for (int dh = 0; dh < 2; ++dh)
#pragma unroll
                for (int eh = 0; eh < 2; ++eh)
                    acc[hh][dh * 2 + eh] = __builtin_amdgcn_mfma_f32_16x16x32_bf16(
                        ka[dh].v8, vb[eh].v8, acc[hh][dh * 2 + eh], 0, 0, 0);
        }
    }

    // ---- store kv partials, MFMA-native layout (R12-verified k2 decode) ----
#pragma unroll
    for (int hh = 0; hh < 2; ++hh) {
        float* dst = pkv + (size_t)blk * (NHEAD * HD * HD) + (wv * 2 + hh) * (HD * HD);
#pragma unroll
        for (int tl = 0; tl < 4; ++tl)
            *(f32x4*)(dst + tl * 256 + l * 4) = acc[hh][tl];
    }

    // ---- ksum: reduce over lg (lane bits 4,5); lanes 0..15 hold channel sums ----
#pragma unroll
    for (int hh = 0; hh < 2; ++hh)
#pragma unroll
        for (int dh = 0; dh < 2; ++dh) {
            ks[hh][dh] += __shfl_xor(ks[hh][dh], 16);
            ks[hh][dh] += __shfl_xor(ks[hh][dh], 32);
        }
    if (l < 16) {
#pragma unroll
        for (int hh = 0; hh < 2; ++hh)
#pragma unroll
            for (int dh = 0; dh < 2; ++dh)
                pksum[(size_t)blk * CC + (wv * 2 + hh) * HD + dh * 16 + l] = ks[hh][dh];
    }
}

// ---------------- Kernel 2: reduce partials; emit kvbT (bf16, [b][h][e][d]) -----
// grid = 512, block = 256. pkv o-layout MFMA-native: h*1024 + tile*256 + l*4 + r,
// tile = dt*2+et (verified correct in R12: absmax 0.0078).
__global__ __launch_bounds__(256) void k2_reduce(
    const float* __restrict__ pkv, const float* __restrict__ pksum,
    unsigned short* __restrict__ kvbT, float* __restrict__ kmean)
{
    const int gid = blockIdx.x * 256 + threadIdx.x;   // over B*8192
    const int b = gid >> 13;
    const int o = gid & 8191;
    float s = 0.f;
#pragma unroll 4
    for (int c = 0; c < NCH; ++c)
        s += pkv[(size_t)(b * NCH + c) * (NHEAD * HD * HD) + o];
    const int hh   = o >> 10;
    const int r1   = o & 1023;
    const int tile = r1 >> 8;
    const int li   = (r1 >> 2) & 63;
    const int rg   = o & 3;
    const int d    = (tile >> 1) * 16 + (li >> 4) * 4 + rg;
    const int e    = (tile & 1) * 16 + (li & 15);
    kvbT[(((size_t)b * NHEAD + hh) * HD + e) * HD + d] = f2bf(s * (1.0f / NN));
    if (o < CC) {
        float ss = 0.f;
#pragma unroll 4
        for (int c = 0; c < NCH; ++c)
            ss += pksum[(size_t)(b * NCH + c) * CC + o];
        kmean[b * CC + o] = ss * (1.0f / NN);
    }
}

// ---------------- Kernel 3: out = MFMA((qr*z) @ kv) + LePE ----------------------
// grid = B*256 (quarter image row each), block = 256 (4 waves)
__global__ __launch_bounds__(256, 2) void k3_out(
    const float* __restrict__ x1, const float* __restrict__ x3,
    const float* __restrict__ pw, const unsigned short* __restrict__ kvbT,
    const float* __restrict__ kmean, const float* __restrict__ lw,
    const float* __restrict__ lb, float* __restrict__ out)
{
    const int blk  = blockIdx.x;      // b*256 + irow*4 + jq
    const int b    = blk >> 8;
    const int irow = (blk >> 2) & 63;
    const int jq   = blk & 3;
    const int j0   = jq << 4;         // 0, 16, 32, 48
    const int t    = threadIdx.x;

    __shared__ unsigned short qr_bf[16 * PADC];   // (qr * z) in bf16, 8.4 KiB
    __shared__ float attn_lds[16][CC];            // 16 KiB

    float wreg[9];
#pragma unroll
    for (int q = 0; q < 9; ++q) wreg[q] = lw[t * 9 + q];
    const float bias = lb[t];

    // ---- stage: q_rope * z  -> bf16 LDS (z folded in; known after shfl reduce) ----
    {
        const int p    = t & 63;       // float4 slot within a pixel's 256 channels
        const int pixo = t >> 6;       // 0..3
        const float4 km4 = *(const float4*)(kmean + b * CC + p * 4);
        const float* x1b = x1 + ((size_t)b * NN + (size_t)irow * 64 + j0) * CC;
        const float* pwb = pw + ((size_t)irow * 64 + j0) * CC;
        float4 xv[4], pvv[4];
#pragma unroll
        for (int s = 0; s < 4; ++s)
            xv[s] = *(const float4*)(x1b + (size_t)(s * 4 + pixo) * CC + p * 4);
#pragma unroll
        for (int s = 0; s < 4; ++s)
            pvv[s] = *(const float4*)(pwb + (size_t)(s * 4 + pixo) * CC + p * 4);
#pragma unroll
        for (int s = 0; s < 4; ++s) {
            const int pix = s * 4 + pixo;   // 0..15 (local)
            float4 q4;
            q4.x = elu1(xv[s].x); q4.y = elu1(xv[s].y);
            q4.z = elu1(xv[s].z); q4.w = elu1(xv[s].w);
            float zp = q4.x * km4.x + q4.y * km4.y + q4.z * km4.z + q4.w * km4.w;
            zp += __shfl_xor(zp, 1);
            zp += __shfl_xor(zp, 2);
            zp += __shfl_xor(zp, 4);        // all 8 lanes of this head have the sum
            const float zin = 1.0f / (zp + 1e-6f);
            ushort4 u;
            u.x = f2bf(q4.x * pvv[s].x * zin);
            u.y = f2bf(q4.y * pvv[s].y * zin);
            u.z = f2bf(q4.z * pvv[s].z * zin);
            u.w = f2bf(q4.w * pvv[s].w * zin);
            *(ushort4*)(&qr_bf[pix * PADC + p * 4]) = u;
        }
    }

    // ---- halo loads issued BEFORE the barrier: cannot be sunk past it ----
    const bool hasU = irow > 0, hasD = irow < 63;
    const float* rU = x3 + ((size_t)b * NN + (size_t)(irow - 1) * 64 + j0) * CC + t;
    const float* rM = x3 + ((size_t)b * NN + (size_t)irow * 64 + j0) * CC + t;
    const float* rD = x3 + ((size_t)b * NN + (size_t)(irow + 1) * 64 + j0) * CC + t;

    float cu[2][10], cm[2][10], cd[2][10];
#pragma unroll
    for (int tt = 0; tt < 2; ++tt)
#pragma unroll
        for (int q = 0; q < 10; ++q) {
            const int col = tt * 8 + q - 1;     // local col in [-1, 16]
            const int g   = j0 + col;           // global col in [-1, 64]
            const bool ok = (g >= 0) && (g < 64);
            const long off = (long)col * CC;
            cm[tt][q] = ok ? rM[off] : 0.f;
            cu[tt][q] = (ok && hasU) ? rU[off] : 0.f;
            cd[tt][q] = (ok && hasD) ? rD[off] : 0.f;
        }

    __syncthreads();

    // ---- MFMA phase: wave w covers heads 2w,2w+1 over all 16 pixels ----
    {
        const int w  = t >> 6;
        const int l  = t & 63;
        const int lr = l & 15;     // A row (pixel) / B col / D col
        const int lg = l >> 4;     // k-group

        bf16x8 af0 = *(const bf16x8*)(&qr_bf[lr * PADC + (w * 2 + 0) * HD + lg * 8]);
        bf16x8 af1 = *(const bf16x8*)(&qr_bf[lr * PADC + (w * 2 + 1) * HD + lg * 8]);

        f32x4 acc[4];
#pragma unroll
        for (int ct = 0; ct < 4; ++ct) {
            const int head = w * 2 + (ct >> 1);
            const int cl   = (ct & 1) * 16 + lr;
            const bf16x8 bf = *(const bf16x8*)(kvbT +
                (((size_t)b * NHEAD + head) * HD + cl) * HD + lg * 8);
            f32x4 z4 = {0.f, 0.f, 0.f, 0.f};
            acc[ct] = __builtin_amdgcn_mfma_f32_16x16x32_bf16(
                (ct < 2) ? af0 : af1, bf, z4, 0, 0, 0);
        }
#pragma unroll
        for (int ct = 0; ct < 4; ++ct) {
            const int c = (w * 2 + (ct >> 1)) * HD + (ct & 1) * 16 + lr;
#pragma unroll
            for (int r = 0; r < 4; ++r)
                attn_lds[lg * 4 + r][c] = acc[ct][r];
        }
    }

    __syncthreads();

    // ---- epilogue: lepe (registers already loaded) + attn + store ----
    float* ob = out + ((size_t)b * NN + (size_t)irow * 64 + j0) * CC + t;
#pragma unroll
    for (int tt = 0; tt < 2; ++tt) {
#pragma unroll
        for (int q = 0; q < 8; ++q) {
            const int jl = tt * 8 + q;          // local pixel 0..15
            float lepe = bias
                + wreg[0] * cu[tt][q] + wreg[1] * cu[tt][q + 1] + wreg[2] * cu[tt][q + 2]
                + wreg[3] * cm[tt][q] + wreg[4] * cm[tt][q + 1] + wreg[5] * cm[tt][q + 2]
                + wreg[6] * cd[tt][q] + wreg[7] * cd[tt][q + 1] + wreg[8] * cd[tt][q + 2];
            __builtin_nontemporal_store(attn_lds[jl][t] + lepe, ob + (long)jl * CC);
        }
    }
}

extern "C" void kernel_launch(void* const* d_in, const int* in_sizes, int n_in,
                              void* d_out, int out_size, void* d_ws, size_t ws_size,
                              hipStream_t stream) {
    const float* x1   = (const float*)d_in[0];
    const float* x2   = (const float*)d_in[1];
    const float* x3   = (const float*)d_in[2];
    const float* posw = (const float*)d_in[3];
    const float* lw   = (const float*)d_in[4];
    const float* lb   = (const float*)d_in[5];
    float* out = (float*)d_out;

    // ws layout: pw | pkv | pksum | kmean | kvbT(ushort)  (~21.6 MB)
    const size_t pw_sz = (size_t)NN * CC;                   // 1M floats
    float* pwb   = (float*)d_ws;
    float* pkv   = pwb + pw_sz;                             // 16*NCH * 8192
    float* pksum = pkv + (size_t)16 * NCH * 8192;           // 16*NCH * 256
    float* kmean = pksum + (size_t)16 * NCH * 256;          // 16 * 256
    unsigned short* kvbT = (unsigned short*)(kmean + (size_t)16 * 256);  // 16*8192

    k0_pw<<<1024, 256, 0, stream>>>(posw, pwb);
    k1_partial<<<BB * NCH, 256, 0, stream>>>(x2, x3, pwb, pkv, pksum);
    k2_reduce<<<512, 256, 0, stream>>>(pkv, pksum, kvbT, kmean);
    k3_out<<<BB * 256, 256, 0, stream>>>(x1, x3, pwb, kvbT, kmean, lw, lb, out);
}